// Round 3
// baseline (457.511 us; speedup 1.0000x reference)
//
#include <hip/hip_runtime.h>
#include <hip/hip_bf16.h>

#define BB 4
#define NH 8
#define HD 64
#define CC 512
#define LL 2048
#define KK 1536   // C*3, K index = t*512 + ci
#define LPAD 2050 // padded rows of xT: row 0 and row 2049 are zeros

typedef float f32x4 __attribute__((ext_vector_type(4)));
typedef short bf16x8 __attribute__((ext_vector_type(8)));

static __device__ __forceinline__ ushort f2bf(float f) {
  union { float f; unsigned u; } v; v.f = f;
  unsigned r = v.u + 0x7fffu + ((v.u >> 16) & 1u);   // RNE
  return (ushort)(r >> 16);
}
static __device__ __forceinline__ void gload16(const ushort* g, ushort* l) {
  __builtin_amdgcn_global_load_lds((const __attribute__((address_space(1))) void*)g,
                                   (__attribute__((address_space(3))) void*)l, 16, 0, 0);
}

// ---------------------------------------------------------------------------
// Weight prep: W[co][ci][t] fp32 -> W'[co][t*512+ci] bf16, for all 4 convs.
// ---------------------------------------------------------------------------
__global__ void prep_w(const float* __restrict__ w0, const float* __restrict__ w1,
                       const float* __restrict__ w2, const float* __restrict__ w3,
                       ushort* __restrict__ out)
{
  int i = blockIdx.x * 256 + threadIdx.x;
  const int per = CC * KK;
  if (i >= 4 * per) return;
  int cidx = i / per;
  int rem  = i - cidx * per;
  int co   = rem / KK;
  int kk   = rem - co * KK;
  int t = kk >> 9, ci = kk & 511;
  const float* w = (cidx == 0) ? w0 : (cidx == 1) ? w1 : (cidx == 2) ? w2 : w3;
  out[i] = f2bf(w[((size_t)co * CC + ci) * 3 + t]);
}

// ---------------------------------------------------------------------------
// Transpose+cast: in[b][c][l] (fp32 or bf16) -> xT[b][l+1][c] bf16, with
// zero rows at l=-1 and l=2048.  64x64 tiles via LDS.
// ---------------------------------------------------------------------------
template<typename TIn>
__global__ __launch_bounds__(256, 2)
void transpose_k(const TIn* __restrict__ in, ushort* __restrict__ outT)
{
  const int b  = blockIdx.z;
  const int c0 = blockIdx.y * 64;
  const int l0 = blockIdx.x * 64;
  const int tid = threadIdx.x;
  __shared__ ushort T[64 * 72];
  const TIn* xb = in + (size_t)b * CC * LL;
  ushort* ob = outT + (size_t)b * (LPAD * CC);
  {
    const int rr = tid >> 4;      // 0..15
    const int f4 = tid & 15;      // 0..15
#pragma unroll
    for (int it = 0; it < 4; ++it) {
      const int cc = rr + it * 16;
      ushort s[4];
      if constexpr (sizeof(TIn) == 4) {
        float4 vv = *(const float4*)((const float*)xb + (size_t)(c0 + cc) * LL + l0 + f4 * 4);
        s[0] = f2bf(vv.x); s[1] = f2bf(vv.y); s[2] = f2bf(vv.z); s[3] = f2bf(vv.w);
      } else {
        *(ushort4*)s = *(const ushort4*)((const ushort*)xb + (size_t)(c0 + cc) * LL + l0 + f4 * 4);
      }
      *(ushort4*)&T[cc * 72 + f4 * 4] = *(ushort4*)s;
    }
  }
  __syncthreads();
  {
    const int lr = tid >> 3;     // 0..31
    const int ch = tid & 7;      // 0..7
#pragma unroll
    for (int it = 0; it < 2; ++it) {
      const int ll = lr + it * 32;
      ushort tmp[8];
#pragma unroll
      for (int e = 0; e < 8; ++e) tmp[e] = T[(ch * 8 + e) * 72 + ll];
      *(uint4*)(ob + (size_t)(l0 + ll + 1) * CC + c0 + ch * 8) = *(uint4*)tmp;
    }
  }
  // zero the halo rows
  if (blockIdx.x == 0 && tid < 8) {
    uint4 z4 = make_uint4(0, 0, 0, 0);
    *(uint4*)(ob + c0 + tid * 8) = z4;
  }
  if (blockIdx.x == (LL / 64 - 1) && tid >= 248) {
    uint4 z4 = make_uint4(0, 0, 0, 0);
    *(uint4*)(ob + (size_t)(LPAD - 1) * CC + c0 + (tid - 248) * 8) = z4;
  }
}

// ---------------------------------------------------------------------------
// conv1d(k=3,same) as implicit GEMM on pre-transposed bf16 input.
// Tile M=64(co) x N=128(l), BK=64.  Staging = 6x global_load_lds(16B)/thread
// with XOR chunk swizzle (applied on the GLOBAL fetch address, since
// global_load_lds forces LDS slot = base + lane*16): physical chunk p of
// row r holds global chunk p^(r&7).  Frag reads land bank-balanced.
// 16 MFMA per barrier pair (m97-level amortization), 24 K-iterations.
// mode 0: out heads [b][h][x][d] bf16 (q,k)
// mode 1: out heads-T [b][h][d][x] bf16 (v)
// mode 2: out [b][co][l] fp32 (final fc)
// ---------------------------------------------------------------------------
__global__ __launch_bounds__(256, 2)
void conv_k(const ushort* __restrict__ xT, const ushort* __restrict__ Wt,
            const float* __restrict__ bias, void* __restrict__ outp, int mode)
{
  const int b   = blockIdx.z;
  const int co0 = blockIdx.y * 64;
  const int l0  = blockIdx.x * 128;
  const int tid = threadIdx.x;
  const int lane = tid & 63;
  const int w    = tid >> 6;
  const int col  = lane & 15, quad = lane >> 4;

  __shared__ ushort Asl[64 * 64];    // 8 KB
  __shared__ ushort Bsl[128 * 64];   // 16 KB

  const ushort* xb = xT + (size_t)b * (LPAD * CC);

  // staging: slot s = round*256 + tid; row = s>>3, phys chunk p = s&7,
  // global chunk g = p ^ (row&7)  (row&7 invariant across +32-row rounds)
  const int sr = tid >> 3;                 // 0..31
  const int g  = (tid & 7) ^ (sr & 7);
  const ushort* ag  = Wt + (size_t)(co0 + sr) * KK + g * 8;
  const ushort* bg  = xb + (size_t)(l0 + sr) * CC + g * 8;
  ushort* alds = &Asl[tid * 8];
  ushort* blds = &Bsl[tid * 8];

  f32x4 acc[2][4] = {};
  const int cm0 = (w & 1) * 32;
  const int cn0 = (w >> 1) * 64;
  const int c7  = col & 7;

  for (int k0 = 0; k0 < KK; k0 += 64) {
    gload16(ag + k0, alds);
    gload16(ag + 32 * KK + k0, alds + 2048);
    gload16(bg + k0, blds);
    gload16(bg + 32 * CC + k0, blds + 2048);
    gload16(bg + 64 * CC + k0, blds + 4096);
    gload16(bg + 96 * CC + k0, blds + 6144);
    __syncthreads();
    bf16x8 af[2][2], bfr[4][2];
#pragma unroll
    for (int i = 0; i < 2; ++i)
#pragma unroll
      for (int kk = 0; kk < 2; ++kk)
        af[i][kk] = *(const bf16x8*)&Asl[(cm0 + i * 16 + col) * 64 + (((kk * 4 + quad) ^ c7) * 8)];
#pragma unroll
    for (int j = 0; j < 4; ++j)
#pragma unroll
      for (int kk = 0; kk < 2; ++kk)
        bfr[j][kk] = *(const bf16x8*)&Bsl[(cn0 + j * 16 + col) * 64 + (((kk * 4 + quad) ^ c7) * 8)];
#pragma unroll
    for (int kk = 0; kk < 2; ++kk)
#pragma unroll
      for (int i = 0; i < 2; ++i)
#pragma unroll
        for (int j = 0; j < 4; ++j)
          acc[i][j] = __builtin_amdgcn_mfma_f32_16x16x32_bf16(af[i][kk], bfr[j][kk], acc[i][j], 0, 0, 0);
    __syncthreads();
  }

  // epilogue: C/D layout row = quad*4+r (co), col = lane&15 (l)
#pragma unroll
  for (int i = 0; i < 2; ++i) {
#pragma unroll
    for (int r = 0; r < 4; ++r) {
      const int co = co0 + cm0 + i * 16 + quad * 4 + r;
      const float bi = bias[co];
#pragma unroll
      for (int j = 0; j < 4; ++j) {
        const int l = l0 + cn0 + j * 16 + col;
        const float y = acc[i][j][r] + bi;
        if (mode == 0) {
          const int xx = (co << 2) + (l >> 9);
          const int hh = (l >> 6) & 7;
          const int dd = l & 63;
          ((ushort*)outp)[((size_t)(b * NH + hh) * LL + xx) * HD + dd] = f2bf(y);
        } else if (mode == 1) {
          const int xx = (co << 2) + (l >> 9);
          const int hh = (l >> 6) & 7;
          const int dd = l & 63;
          ((ushort*)outp)[((size_t)(b * NH + hh) * HD + dd) * LL + xx] = f2bf(y);
        } else {
          ((float*)outp)[(size_t)(b * CC + co) * LL + l] = y;
        }
      }
    }
  }
}

// ---------------------------------------------------------------------------
// Attention v2: 512 threads = 8 waves x 16 Q-rows; grid (16,32) -> 16 waves/CU.
// No max-subtraction (logits bounded): O += exp(S/64) V.  Denominator via
// MFMA against a constant all-ones B fragment (2 extra MFMA/y-tile replaces
// the 16-shfl butterfly).  P round-trips through wave-private LDS rows ->
// zero barriers.  Output scattered to [b][c][l] bf16 for the fc conv.
// ---------------------------------------------------------------------------
__global__ __launch_bounds__(512, 4)
void attn_k(const ushort* __restrict__ qh, const ushort* __restrict__ kh,
            const ushort* __restrict__ vt, ushort* __restrict__ o)
{
  const int x0 = blockIdx.x * 128;
  const int bh = blockIdx.y;
  const int b = bh >> 3, h = bh & 7;
  const int tid = threadIdx.x, lane = tid & 63, wv = tid >> 6;
  const int col = lane & 15, quad = lane >> 4;
  const int wx = wv * 16;   // wave-private 16 x-rows

  __shared__ ushort Ps[128 * 88];   // 8 waves x 16 rows, stride 88 (bank-balanced)

  const ushort* Qg = qh + (size_t)bh * (LL * HD);
  const ushort* Kg = kh + (size_t)bh * (LL * HD);
  const ushort* Vg = vt + (size_t)bh * (HD * LL);

  // Q fragments straight from global (A-operand layout: m=lane&15, k=quad*8+j)
  bf16x8 aq[2];
#pragma unroll
  for (int kk = 0; kk < 2; ++kk)
    aq[kk] = *(const bf16x8*)(Qg + (size_t)(x0 + wx + col) * HD + kk * 32 + quad * 8);

  const short one = (short)0x3F80;  // bf16 1.0
  const bf16x8 ones = {one, one, one, one, one, one, one, one};

  f32x4 oacc[4] = {};
  f32x4 dacc = {};

  for (int yt = 0; yt < 32; ++yt) {
    const int y0 = yt * 64;
    // S = Q K^T  (K rows are the B-operand: Bt[n=y][k=d])
    f32x4 sacc[4] = {};
#pragma unroll
    for (int kk = 0; kk < 2; ++kk)
#pragma unroll
      for (int j = 0; j < 4; ++j) {
        bf16x8 bk = *(const bf16x8*)(Kg + (size_t)(y0 + j * 16 + col) * HD + kk * 32 + quad * 8);
        sacc[j] = __builtin_amdgcn_mfma_f32_16x16x32_bf16(aq[kk], bk, sacc[j], 0, 0, 0);
      }
    // exp, packed bf16 cvt, P -> LDS (wave-private rows)
#pragma unroll
    for (int j = 0; j < 4; ++j)
#pragma unroll
      for (int r = 0; r < 4; r += 2) {
        const float p0 = __expf(sacc[j][r] * 0.015625f);
        const float p1 = __expf(sacc[j][r + 1] * 0.015625f);
        union { __hip_bfloat162 h; ushort2 u; } cv;
        cv.h = __float22bfloat162_rn(make_float2(p0, p1));
        Ps[(wx + quad * 4 + r) * 88 + j * 16 + col] = cv.u.x;
        Ps[(wx + quad * 4 + r + 1) * 88 + j * 16 + col] = cv.u.y;
      }
    // O += P V ; denom += P * ones   (V^T rows are the B-operand: Bt[n=d][k=y])
#pragma unroll
    for (int kk = 0; kk < 2; ++kk) {
      bf16x8 ap = *(const bf16x8*)&Ps[(wx + col) * 88 + kk * 32 + quad * 8];
      dacc = __builtin_amdgcn_mfma_f32_16x16x32_bf16(ap, ones, dacc, 0, 0, 0);
#pragma unroll
      for (int j = 0; j < 4; ++j) {
        bf16x8 bv = *(const bf16x8*)(Vg + (size_t)(j * 16 + col) * LL + y0 + kk * 32 + quad * 8);
        oacc[j] = __builtin_amdgcn_mfma_f32_16x16x32_bf16(ap, bv, oacc[j], 0, 0, 0);
      }
    }
  }

  // normalize + scatter to [b][c][l] bf16  (flat = x*512 + h*64 + d)
#pragma unroll
  for (int r = 0; r < 4; ++r) {
    const int xg = x0 + wx + quad * 4 + r;
    const float inv = 1.f / dacc[r];
#pragma unroll
    for (int j = 0; j < 4; ++j) {
      const int d = j * 16 + col;
      const int flat = xg * 512 + h * 64 + d;
      const int c = flat >> 11, l = flat & 2047;
      o[((size_t)(b * CC + c) << 11) + l] = f2bf(oacc[j][r] * inv);
    }
  }
}

// ---------------------------------------------------------------------------
extern "C" void kernel_launch(void* const* d_in, const int* in_sizes, int n_in,
                              void* d_out, int out_size, void* d_ws, size_t ws_size,
                              hipStream_t stream) {
  const float* q    = (const float*)d_in[0];
  const float* k    = (const float*)d_in[1];
  const float* v    = (const float*)d_in[2];
  const float* wq_w = (const float*)d_in[3];
  const float* wq_b = (const float*)d_in[4];
  const float* wk_w = (const float*)d_in[5];
  const float* wk_b = (const float*)d_in[6];
  const float* wv_w = (const float*)d_in[7];
  const float* wv_b = (const float*)d_in[8];
  const float* fc_w = (const float*)d_in[9];
  const float* fc_b = (const float*)d_in[10];

  char* ws = (char*)d_ws;
  const size_t WSZ = (size_t)CC * KK * sizeof(ushort);            // 1.5 MB per conv
  const size_t HSZ = (size_t)BB * NH * LL * HD * sizeof(ushort);  // 8.39 MB per head tensor
  const size_t XSZ = (size_t)BB * LPAD * CC * sizeof(ushort);     // 8.40 MB padded xT

  ushort* Wt  = (ushort*)(ws);                         // 4 weight sets, 6 MB
  ushort* qh  = (ushort*)(ws + 4 * WSZ);
  ushort* kh  = (ushort*)(ws + 4 * WSZ + HSZ);
  ushort* vt  = (ushort*)(ws + 4 * WSZ + 2 * HSZ);
  ushort* xTb = (ushort*)(ws + 4 * WSZ + 3 * HSZ);     // shared transpose buffer
  // aliases (lifetimes disjoint):
  ushort* ob  = xTb;            // attn output [b][c][l]; xT dead after v-conv
  ushort* obT = qh;             // padded transpose of ob; qh(+kh) dead after attn
  // total ws use: 4*WSZ + 3*HSZ + XSZ  ~= 39.85 MB (same as round 1)

  prep_w<<<(4 * CC * KK + 255) / 256, 256, 0, stream>>>(wq_w, wk_w, wv_w, fc_w, Wt);

  // q
  transpose_k<float><<<dim3(32, 8, 4), 256, 0, stream>>>(q, xTb);
  conv_k<<<dim3(16, 8, 4), 256, 0, stream>>>(xTb, Wt + 0 * CC * KK, wq_b, qh, 0);
  // k
  transpose_k<float><<<dim3(32, 8, 4), 256, 0, stream>>>(k, xTb);
  conv_k<<<dim3(16, 8, 4), 256, 0, stream>>>(xTb, Wt + 1 * CC * KK, wk_b, kh, 0);
  // v
  transpose_k<float><<<dim3(32, 8, 4), 256, 0, stream>>>(v, xTb);
  conv_k<<<dim3(16, 8, 4), 256, 0, stream>>>(xTb, Wt + 2 * CC * KK, wv_b, vt, 1);

  attn_k<<<dim3(16, 32), 512, 0, stream>>>(qh, kh, vt, ob);

  transpose_k<ushort><<<dim3(32, 8, 4), 256, 0, stream>>>(ob, obT);
  conv_k<<<dim3(16, 8, 4), 256, 0, stream>>>(obT, Wt + 3 * CC * KK, fc_b, (float*)d_out, 2);
}

// Round 4
// 353.538 us; speedup vs baseline: 1.2941x; 1.2941x over previous
//
#include <hip/hip_runtime.h>
#include <hip/hip_bf16.h>

#define BB 4
#define NH 8
#define HD 64
#define CC 512
#define LL 2048
#define KK 1536   // C*3, K index = t*512 + ci
#define LPAD 2050 // padded rows of xT: row 0 and row 2049 are zeros

typedef float f32x4 __attribute__((ext_vector_type(4)));
typedef short bf16x8 __attribute__((ext_vector_type(8)));

static __device__ __forceinline__ ushort f2bf(float f) {
  union { float f; unsigned u; } v; v.f = f;
  unsigned r = v.u + 0x7fffu + ((v.u >> 16) & 1u);   // RNE
  return (ushort)(r >> 16);
}
static __device__ __forceinline__ void gload16(const ushort* g, ushort* l) {
  __builtin_amdgcn_global_load_lds((const __attribute__((address_space(1))) void*)g,
                                   (__attribute__((address_space(3))) void*)l, 16, 0, 0);
}

// ---------------------------------------------------------------------------
// Weight prep: W[co][ci][t] fp32 -> W'[co][t*512+ci] bf16, for all 4 convs.
// ---------------------------------------------------------------------------
__global__ void prep_w(const float* __restrict__ w0, const float* __restrict__ w1,
                       const float* __restrict__ w2, const float* __restrict__ w3,
                       ushort* __restrict__ out)
{
  int i = blockIdx.x * 256 + threadIdx.x;
  const int per = CC * KK;
  if (i >= 4 * per) return;
  int cidx = i / per;
  int rem  = i - cidx * per;
  int co   = rem / KK;
  int kk   = rem - co * KK;
  int t = kk >> 9, ci = kk & 511;
  const float* w = (cidx == 0) ? w0 : (cidx == 1) ? w1 : (cidx == 2) ? w2 : w3;
  out[i] = f2bf(w[((size_t)co * CC + ci) * 3 + t]);
}

// ---------------------------------------------------------------------------
// Transpose+cast: in[b][c][l] (fp32 or bf16) -> xT[b][l+1][c] bf16, with
// zero rows at l=-1 and l=2048.  64x64 tiles via LDS.
// ---------------------------------------------------------------------------
template<typename TIn>
__global__ __launch_bounds__(256, 2)
void transpose_k(const TIn* __restrict__ in, ushort* __restrict__ outT)
{
  const int b  = blockIdx.z;
  const int c0 = blockIdx.y * 64;
  const int l0 = blockIdx.x * 64;
  const int tid = threadIdx.x;
  __shared__ ushort T[64 * 72];
  const TIn* xb = in + (size_t)b * CC * LL;
  ushort* ob = outT + (size_t)b * (LPAD * CC);
  {
    const int rr = tid >> 4;      // 0..15
    const int f4 = tid & 15;      // 0..15
#pragma unroll
    for (int it = 0; it < 4; ++it) {
      const int cc = rr + it * 16;
      ushort s[4];
      if constexpr (sizeof(TIn) == 4) {
        float4 vv = *(const float4*)((const float*)xb + (size_t)(c0 + cc) * LL + l0 + f4 * 4);
        s[0] = f2bf(vv.x); s[1] = f2bf(vv.y); s[2] = f2bf(vv.z); s[3] = f2bf(vv.w);
      } else {
        *(ushort4*)s = *(const ushort4*)((const ushort*)xb + (size_t)(c0 + cc) * LL + l0 + f4 * 4);
      }
      *(ushort4*)&T[cc * 72 + f4 * 4] = *(ushort4*)s;
    }
  }
  __syncthreads();
  {
    const int lr = tid >> 3;     // 0..31
    const int ch = tid & 7;      // 0..7
#pragma unroll
    for (int it = 0; it < 2; ++it) {
      const int ll = lr + it * 32;
      ushort tmp[8];
#pragma unroll
      for (int e = 0; e < 8; ++e) tmp[e] = T[(ch * 8 + e) * 72 + ll];
      *(uint4*)(ob + (size_t)(l0 + ll + 1) * CC + c0 + ch * 8) = *(uint4*)tmp;
    }
  }
  // zero the halo rows
  if (blockIdx.x == 0 && tid < 8) {
    uint4 z4 = make_uint4(0, 0, 0, 0);
    *(uint4*)(ob + c0 + tid * 8) = z4;
  }
  if (blockIdx.x == (LL / 64 - 1) && tid >= 248) {
    uint4 z4 = make_uint4(0, 0, 0, 0);
    *(uint4*)(ob + (size_t)(LPAD - 1) * CC + c0 + (tid - 248) * 8) = z4;
  }
}

// ---------------------------------------------------------------------------
// conv1d(k=3,same) as implicit GEMM on pre-transposed bf16 input.
// Tile M=64(co) x N=128(l), BK=64.  Staging = 6x global_load_lds(16B)/thread
// with XOR chunk swizzle on the GLOBAL fetch address.
// mode 0: out heads [b][h][x][d] bf16 (q,k)
// mode 1: out heads-T [b][h][d][x] bf16 (v)
// mode 2: out [b][co][l] fp32 (final fc)
// ---------------------------------------------------------------------------
__global__ __launch_bounds__(256, 2)
void conv_k(const ushort* __restrict__ xT, const ushort* __restrict__ Wt,
            const float* __restrict__ bias, void* __restrict__ outp, int mode)
{
  const int b   = blockIdx.z;
  const int co0 = blockIdx.y * 64;
  const int l0  = blockIdx.x * 128;
  const int tid = threadIdx.x;
  const int lane = tid & 63;
  const int w    = tid >> 6;
  const int col  = lane & 15, quad = lane >> 4;

  __shared__ ushort Asl[64 * 64];    // 8 KB
  __shared__ ushort Bsl[128 * 64];   // 16 KB

  const ushort* xb = xT + (size_t)b * (LPAD * CC);

  const int sr = tid >> 3;                 // 0..31
  const int g  = (tid & 7) ^ (sr & 7);
  const ushort* ag  = Wt + (size_t)(co0 + sr) * KK + g * 8;
  const ushort* bg  = xb + (size_t)(l0 + sr) * CC + g * 8;
  ushort* alds = &Asl[tid * 8];
  ushort* blds = &Bsl[tid * 8];

  f32x4 acc[2][4] = {};
  const int cm0 = (w & 1) * 32;
  const int cn0 = (w >> 1) * 64;
  const int c7  = col & 7;

  for (int k0 = 0; k0 < KK; k0 += 64) {
    gload16(ag + k0, alds);
    gload16(ag + 32 * KK + k0, alds + 2048);
    gload16(bg + k0, blds);
    gload16(bg + 32 * CC + k0, blds + 2048);
    gload16(bg + 64 * CC + k0, blds + 4096);
    gload16(bg + 96 * CC + k0, blds + 6144);
    __syncthreads();
    bf16x8 af[2][2], bfr[4][2];
#pragma unroll
    for (int i = 0; i < 2; ++i)
#pragma unroll
      for (int kk = 0; kk < 2; ++kk)
        af[i][kk] = *(const bf16x8*)&Asl[(cm0 + i * 16 + col) * 64 + (((kk * 4 + quad) ^ c7) * 8)];
#pragma unroll
    for (int j = 0; j < 4; ++j)
#pragma unroll
      for (int kk = 0; kk < 2; ++kk)
        bfr[j][kk] = *(const bf16x8*)&Bsl[(cn0 + j * 16 + col) * 64 + (((kk * 4 + quad) ^ c7) * 8)];
#pragma unroll
    for (int kk = 0; kk < 2; ++kk)
#pragma unroll
      for (int i = 0; i < 2; ++i)
#pragma unroll
        for (int j = 0; j < 4; ++j)
          acc[i][j] = __builtin_amdgcn_mfma_f32_16x16x32_bf16(af[i][kk], bfr[j][kk], acc[i][j], 0, 0, 0);
    __syncthreads();
  }

  // epilogue: C/D layout row = quad*4+r (co), col = lane&15 (l)
#pragma unroll
  for (int i = 0; i < 2; ++i) {
#pragma unroll
    for (int r = 0; r < 4; ++r) {
      const int co = co0 + cm0 + i * 16 + quad * 4 + r;
      const float bi = bias[co];
#pragma unroll
      for (int j = 0; j < 4; ++j) {
        const int l = l0 + cn0 + j * 16 + col;
        const float y = acc[i][j][r] + bi;
        if (mode == 0) {
          const int xx = (co << 2) + (l >> 9);
          const int hh = (l >> 6) & 7;
          const int dd = l & 63;
          ((ushort*)outp)[((size_t)(b * NH + hh) * LL + xx) * HD + dd] = f2bf(y);
        } else if (mode == 1) {
          const int xx = (co << 2) + (l >> 9);
          const int hh = (l >> 6) & 7;
          const int dd = l & 63;
          ((ushort*)outp)[((size_t)(b * NH + hh) * HD + dd) * LL + xx] = f2bf(y);
        } else {
          ((float*)outp)[(size_t)(b * CC + co) * LL + l] = y;
        }
      }
    }
  }
}

// ---------------------------------------------------------------------------
// Attention v3 (split-y): block = 4 waves sharing the SAME 32 Q-rows; wave wv
// covers y-range [wv*512, wv*512+512) — partials are purely additive since
// there is no max-subtraction.  Grid (64,32) = 2048 blocks -> ~24-28 waves/CU.
// Per-wave tile identical to round 2 (32 rows, 2x reuse of K/V fragments).
// Denominator via ones-MFMA.  Epilogue: staggered cross-wave reduction in the
// dead Ps LDS region (f32, stride-66 rows), wave 0 normalizes and stores.
// ---------------------------------------------------------------------------
__global__ __launch_bounds__(256, 4)
void attn_k(const ushort* __restrict__ qh, const ushort* __restrict__ kh,
            const ushort* __restrict__ vt, ushort* __restrict__ o)
{
  const int x0 = blockIdx.x * 32;
  const int bh = blockIdx.y;
  const int b = bh >> 3, h = bh & 7;
  const int tid = threadIdx.x, lane = tid & 63, wv = tid >> 6;
  const int col = lane & 15, quad = lane >> 4;
  const int wx = wv * 32;          // wave-private P rows

  __shared__ ushort Ps[128 * 88];  // 22528 B; re-used as f32 reduce slots later

  const ushort* Qg = qh + (size_t)bh * (LL * HD);
  const ushort* Kg = kh + (size_t)bh * (LL * HD);
  const ushort* Vg = vt + (size_t)bh * (HD * LL);

  // Q fragments (A-operand layout: m=lane&15, k=quad*8+j)
  bf16x8 aq[2][2];
#pragma unroll
  for (int i = 0; i < 2; ++i)
#pragma unroll
    for (int kk = 0; kk < 2; ++kk)
      aq[i][kk] = *(const bf16x8*)(Qg + (size_t)(x0 + i * 16 + col) * HD + kk * 32 + quad * 8);

  const short one = (short)0x3F80;  // bf16 1.0
  const bf16x8 ones = {one, one, one, one, one, one, one, one};

  f32x4 oacc[2][4] = {};
  f32x4 dacc[2] = {};

  const int ybeg = wv * 8;        // 8 y-tiles of 64 per wave
  for (int yt = ybeg; yt < ybeg + 8; ++yt) {
    const int y0 = yt * 64;
    // S = Q K^T
    f32x4 sacc[2][4] = {};
#pragma unroll
    for (int kk = 0; kk < 2; ++kk)
#pragma unroll
      for (int j = 0; j < 4; ++j) {
        bf16x8 bk = *(const bf16x8*)(Kg + (size_t)(y0 + j * 16 + col) * HD + kk * 32 + quad * 8);
        sacc[0][j] = __builtin_amdgcn_mfma_f32_16x16x32_bf16(aq[0][kk], bk, sacc[0][j], 0, 0, 0);
        sacc[1][j] = __builtin_amdgcn_mfma_f32_16x16x32_bf16(aq[1][kk], bk, sacc[1][j], 0, 0, 0);
      }
    // exp, packed bf16 cvt, P -> wave-private LDS rows
#pragma unroll
    for (int i = 0; i < 2; ++i)
#pragma unroll
      for (int j = 0; j < 4; ++j)
#pragma unroll
        for (int r = 0; r < 4; r += 2) {
          const float p0 = __expf(sacc[i][j][r] * 0.015625f);
          const float p1 = __expf(sacc[i][j][r + 1] * 0.015625f);
          union { __hip_bfloat162 h; ushort2 u; } cv;
          cv.h = __float22bfloat162_rn(make_float2(p0, p1));
          Ps[(wx + i * 16 + quad * 4 + r) * 88 + j * 16 + col] = cv.u.x;
          Ps[(wx + i * 16 + quad * 4 + r + 1) * 88 + j * 16 + col] = cv.u.y;
        }
    // O += P V ; denom += P * ones
#pragma unroll
    for (int kk = 0; kk < 2; ++kk) {
      bf16x8 ap0 = *(const bf16x8*)&Ps[(wx + col) * 88 + kk * 32 + quad * 8];
      bf16x8 ap1 = *(const bf16x8*)&Ps[(wx + 16 + col) * 88 + kk * 32 + quad * 8];
      dacc[0] = __builtin_amdgcn_mfma_f32_16x16x32_bf16(ap0, ones, dacc[0], 0, 0, 0);
      dacc[1] = __builtin_amdgcn_mfma_f32_16x16x32_bf16(ap1, ones, dacc[1], 0, 0, 0);
#pragma unroll
      for (int j = 0; j < 4; ++j) {
        bf16x8 bv = *(const bf16x8*)(Vg + (size_t)(j * 16 + col) * LL + y0 + kk * 32 + quad * 8);
        oacc[0][j] = __builtin_amdgcn_mfma_f32_16x16x32_bf16(ap0, bv, oacc[0][j], 0, 0, 0);
        oacc[1][j] = __builtin_amdgcn_mfma_f32_16x16x32_bf16(ap1, bv, oacc[1][j], 0, 0, 0);
      }
    }
  }

  // ---- cross-wave reduction (Ps region is dead after this barrier) ----
  float* F  = (float*)Ps;             // 2 slots x 32 rows x stride 66 f32
  float* Dd = (float*)(Ps + 8448);    // 2 slots x 32 f32
  __syncthreads();
  if (wv >= 2) {
    const int s = wv - 2;
#pragma unroll
    for (int i = 0; i < 2; ++i) {
#pragma unroll
      for (int r = 0; r < 4; ++r) {
        const int row = i * 16 + quad * 4 + r;
#pragma unroll
        for (int j = 0; j < 4; ++j)
          F[s * 2112 + row * 66 + j * 16 + col] = oacc[i][j][r];
        Dd[s * 32 + row] = dacc[i][r];
      }
    }
  }
  __syncthreads();
  if (wv < 2) {
    const int s = wv;
#pragma unroll
    for (int i = 0; i < 2; ++i)
#pragma unroll
      for (int r = 0; r < 4; ++r) {
        const int row = i * 16 + quad * 4 + r;
#pragma unroll
        for (int j = 0; j < 4; ++j)
          oacc[i][j][r] += F[s * 2112 + row * 66 + j * 16 + col];
        dacc[i][r] += Dd[s * 32 + row];
      }
  }
  __syncthreads();
  if (wv == 1) {
#pragma unroll
    for (int i = 0; i < 2; ++i)
#pragma unroll
      for (int r = 0; r < 4; ++r) {
        const int row = i * 16 + quad * 4 + r;
#pragma unroll
        for (int j = 0; j < 4; ++j)
          F[row * 66 + j * 16 + col] = oacc[i][j][r];
        Dd[row] = dacc[i][r];
      }
  }
  __syncthreads();
  if (wv == 0) {
#pragma unroll
    for (int i = 0; i < 2; ++i)
#pragma unroll
      for (int r = 0; r < 4; ++r) {
        const int row = i * 16 + quad * 4 + r;
        const int xg = x0 + row;
        float dn = dacc[i][r] + Dd[row];
        const float inv = 1.f / dn;
#pragma unroll
        for (int j = 0; j < 4; ++j) {
          const float ov = oacc[i][j][r] + F[row * 66 + j * 16 + col];
          const int d = j * 16 + col;
          const int flat = xg * 512 + h * 64 + d;
          const int c = flat >> 11, l = flat & 2047;
          o[((size_t)(b * CC + c) << 11) + l] = f2bf(ov * inv);
        }
      }
  }
}

// ---------------------------------------------------------------------------
extern "C" void kernel_launch(void* const* d_in, const int* in_sizes, int n_in,
                              void* d_out, int out_size, void* d_ws, size_t ws_size,
                              hipStream_t stream) {
  const float* q    = (const float*)d_in[0];
  const float* k    = (const float*)d_in[1];
  const float* v    = (const float*)d_in[2];
  const float* wq_w = (const float*)d_in[3];
  const float* wq_b = (const float*)d_in[4];
  const float* wk_w = (const float*)d_in[5];
  const float* wk_b = (const float*)d_in[6];
  const float* wv_w = (const float*)d_in[7];
  const float* wv_b = (const float*)d_in[8];
  const float* fc_w = (const float*)d_in[9];
  const float* fc_b = (const float*)d_in[10];

  char* ws = (char*)d_ws;
  const size_t WSZ = (size_t)CC * KK * sizeof(ushort);            // 1.5 MB per conv
  const size_t HSZ = (size_t)BB * NH * LL * HD * sizeof(ushort);  // 8.39 MB per head tensor
  const size_t XSZ = (size_t)BB * LPAD * CC * sizeof(ushort);     // 8.40 MB padded xT

  ushort* Wt  = (ushort*)(ws);                         // 4 weight sets, 6 MB
  ushort* qh  = (ushort*)(ws + 4 * WSZ);
  ushort* kh  = (ushort*)(ws + 4 * WSZ + HSZ);
  ushort* vt  = (ushort*)(ws + 4 * WSZ + 2 * HSZ);
  ushort* xTb = (ushort*)(ws + 4 * WSZ + 3 * HSZ);     // shared transpose buffer
  // aliases (lifetimes disjoint):
  ushort* ob  = xTb;            // attn output [b][c][l]; xT dead after v-conv
  ushort* obT = qh;             // padded transpose of ob; qh(+kh) dead after attn
  // total ws use: 4*WSZ + 3*HSZ + XSZ  ~= 39.85 MB

  prep_w<<<(4 * CC * KK + 255) / 256, 256, 0, stream>>>(wq_w, wk_w, wv_w, fc_w, Wt);

  // q
  transpose_k<float><<<dim3(32, 8, 4), 256, 0, stream>>>(q, xTb);
  conv_k<<<dim3(16, 8, 4), 256, 0, stream>>>(xTb, Wt + 0 * CC * KK, wq_b, qh, 0);
  // k
  transpose_k<float><<<dim3(32, 8, 4), 256, 0, stream>>>(k, xTb);
  conv_k<<<dim3(16, 8, 4), 256, 0, stream>>>(xTb, Wt + 1 * CC * KK, wk_b, kh, 0);
  // v
  transpose_k<float><<<dim3(32, 8, 4), 256, 0, stream>>>(v, xTb);
  conv_k<<<dim3(16, 8, 4), 256, 0, stream>>>(xTb, Wt + 2 * CC * KK, wv_b, vt, 1);

  attn_k<<<dim3(64, 32), 256, 0, stream>>>(qh, kh, vt, ob);

  transpose_k<ushort><<<dim3(32, 8, 4), 256, 0, stream>>>(ob, obT);
  conv_k<<<dim3(16, 8, 4), 256, 0, stream>>>(obT, Wt + 3 * CC * KK, fc_b, (float*)d_out, 2);
}

// Round 5
// 342.667 us; speedup vs baseline: 1.3351x; 1.0317x over previous
//
#include <hip/hip_runtime.h>
#include <hip/hip_bf16.h>

#define BB 4
#define NH 8
#define HD 64
#define CC 512
#define LL 2048
#define KK 1536   // C*3, K index = t*512 + ci
#define LPAD 2050 // padded rows of xT: row 0 and row 2049 are zeros

typedef float f32x4 __attribute__((ext_vector_type(4)));
typedef short bf16x8 __attribute__((ext_vector_type(8)));

static __device__ __forceinline__ ushort f2bf(float f) {
  union { float f; unsigned u; } v; v.f = f;
  unsigned r = v.u + 0x7fffu + ((v.u >> 16) & 1u);   // RNE
  return (ushort)(r >> 16);
}
static __device__ __forceinline__ void gload16(const ushort* g, ushort* l) {
  __builtin_amdgcn_global_load_lds((const __attribute__((address_space(1))) void*)g,
                                   (__attribute__((address_space(3))) void*)l, 16, 0, 0);
}

// ---------------------------------------------------------------------------
// Weight prep: W[co][ci][t] fp32 -> W'[co][t*512+ci] bf16, for all 4 convs.
// ---------------------------------------------------------------------------
__global__ void prep_w(const float* __restrict__ w0, const float* __restrict__ w1,
                       const float* __restrict__ w2, const float* __restrict__ w3,
                       ushort* __restrict__ out)
{
  int i = blockIdx.x * 256 + threadIdx.x;
  const int per = CC * KK;
  if (i >= 4 * per) return;
  int cidx = i / per;
  int rem  = i - cidx * per;
  int co   = rem / KK;
  int kk   = rem - co * KK;
  int t = kk >> 9, ci = kk & 511;
  const float* w = (cidx == 0) ? w0 : (cidx == 1) ? w1 : (cidx == 2) ? w2 : w3;
  out[i] = f2bf(w[((size_t)co * CC + ci) * 3 + t]);
}

// ---------------------------------------------------------------------------
// Transpose+cast body: xb[c][l] (fp32 or bf16) -> ob[l+1][c] bf16, zero rows
// at l=-1 and l=2048.  64x64 tiles via LDS.
// ---------------------------------------------------------------------------
template<typename TIn>
__device__ __forceinline__ void transpose_body(const TIn* __restrict__ xb,
                                               ushort* __restrict__ ob)
{
  const int c0 = blockIdx.y * 64;
  const int l0 = blockIdx.x * 64;
  const int tid = threadIdx.x;
  __shared__ ushort T[64 * 72];
  {
    const int rr = tid >> 4;      // 0..15
    const int f4 = tid & 15;      // 0..15
#pragma unroll
    for (int it = 0; it < 4; ++it) {
      const int cc = rr + it * 16;
      ushort s[4];
      if constexpr (sizeof(TIn) == 4) {
        float4 vv = *(const float4*)((const float*)xb + (size_t)(c0 + cc) * LL + l0 + f4 * 4);
        s[0] = f2bf(vv.x); s[1] = f2bf(vv.y); s[2] = f2bf(vv.z); s[3] = f2bf(vv.w);
      } else {
        *(ushort4*)s = *(const ushort4*)((const ushort*)xb + (size_t)(c0 + cc) * LL + l0 + f4 * 4);
      }
      *(ushort4*)&T[cc * 72 + f4 * 4] = *(ushort4*)s;
    }
  }
  __syncthreads();
  {
    const int lr = tid >> 3;     // 0..31
    const int ch = tid & 7;      // 0..7
#pragma unroll
    for (int it = 0; it < 2; ++it) {
      const int ll = lr + it * 32;
      ushort tmp[8];
#pragma unroll
      for (int e = 0; e < 8; ++e) tmp[e] = T[(ch * 8 + e) * 72 + ll];
      *(uint4*)(ob + (size_t)(l0 + ll + 1) * CC + c0 + ch * 8) = *(uint4*)tmp;
    }
  }
  // zero the halo rows
  if (blockIdx.x == 0 && tid < 8) {
    uint4 z4 = make_uint4(0, 0, 0, 0);
    *(uint4*)(ob + c0 + tid * 8) = z4;
  }
  if (blockIdx.x == (LL / 64 - 1) && tid >= 248) {
    uint4 z4 = make_uint4(0, 0, 0, 0);
    *(uint4*)(ob + (size_t)(LPAD - 1) * CC + c0 + (tid - 248) * 8) = z4;
  }
}

template<typename TIn>
__global__ __launch_bounds__(256, 2)
void transpose_k(const TIn* __restrict__ in, ushort* __restrict__ outT)
{
  const int b = blockIdx.z;
  transpose_body<TIn>(in + (size_t)b * CC * LL, outT + (size_t)b * (LPAD * CC));
}

// fused q/k/v transpose: z = var*4 + b
__global__ __launch_bounds__(256, 2)
void transpose3_k(const float* __restrict__ q, const float* __restrict__ k,
                  const float* __restrict__ v, ushort* __restrict__ xq,
                  ushort* __restrict__ xk, ushort* __restrict__ xv)
{
  const int z = blockIdx.z;
  const int b = z & 3, var = z >> 2;
  const float* in = (var == 0) ? q : (var == 1) ? k : v;
  ushort* out = (var == 0) ? xq : (var == 1) ? xk : xv;
  transpose_body<float>(in + (size_t)b * CC * LL, out + (size_t)b * (LPAD * CC));
}

// ---------------------------------------------------------------------------
// conv1d(k=3,same) as implicit GEMM on pre-transposed bf16 input.
// Tile M=64(co) x N=128(l), BK=64.  Staging = 6x global_load_lds(16B)/thread
// with XOR chunk swizzle on the GLOBAL fetch address.
// mode 0: out heads [b][h][x][d] bf16 (q,k)
// mode 1: out heads-T [b][h][d][x] bf16 (v)
// mode 2: out [b][co][l] fp32 (final fc)
// ---------------------------------------------------------------------------
__device__ __forceinline__ void conv_body(const ushort* __restrict__ xb,
                                          const ushort* __restrict__ Wt,
                                          const float* __restrict__ bias,
                                          void* __restrict__ outp, int mode, int b)
{
  const int co0 = blockIdx.y * 64;
  const int l0  = blockIdx.x * 128;
  const int tid = threadIdx.x;
  const int lane = tid & 63;
  const int w    = tid >> 6;
  const int col  = lane & 15, quad = lane >> 4;

  __shared__ ushort Asl[64 * 64];    // 8 KB
  __shared__ ushort Bsl[128 * 64];   // 16 KB

  const int sr = tid >> 3;                 // 0..31
  const int g  = (tid & 7) ^ (sr & 7);
  const ushort* ag  = Wt + (size_t)(co0 + sr) * KK + g * 8;
  const ushort* bg  = xb + (size_t)(l0 + sr) * CC + g * 8;
  ushort* alds = &Asl[tid * 8];
  ushort* blds = &Bsl[tid * 8];

  f32x4 acc[2][4] = {};
  const int cm0 = (w & 1) * 32;
  const int cn0 = (w >> 1) * 64;
  const int c7  = col & 7;

  for (int k0 = 0; k0 < KK; k0 += 64) {
    gload16(ag + k0, alds);
    gload16(ag + 32 * KK + k0, alds + 2048);
    gload16(bg + k0, blds);
    gload16(bg + 32 * CC + k0, blds + 2048);
    gload16(bg + 64 * CC + k0, blds + 4096);
    gload16(bg + 96 * CC + k0, blds + 6144);
    __syncthreads();
    bf16x8 af[2][2], bfr[4][2];
#pragma unroll
    for (int i = 0; i < 2; ++i)
#pragma unroll
      for (int kk = 0; kk < 2; ++kk)
        af[i][kk] = *(const bf16x8*)&Asl[(cm0 + i * 16 + col) * 64 + (((kk * 4 + quad) ^ c7) * 8)];
#pragma unroll
    for (int j = 0; j < 4; ++j)
#pragma unroll
      for (int kk = 0; kk < 2; ++kk)
        bfr[j][kk] = *(const bf16x8*)&Bsl[(cn0 + j * 16 + col) * 64 + (((kk * 4 + quad) ^ c7) * 8)];
#pragma unroll
    for (int kk = 0; kk < 2; ++kk)
#pragma unroll
      for (int i = 0; i < 2; ++i)
#pragma unroll
        for (int j = 0; j < 4; ++j)
          acc[i][j] = __builtin_amdgcn_mfma_f32_16x16x32_bf16(af[i][kk], bfr[j][kk], acc[i][j], 0, 0, 0);
    __syncthreads();
  }

  // epilogue: C/D layout row = quad*4+r (co), col = lane&15 (l)
#pragma unroll
  for (int i = 0; i < 2; ++i) {
#pragma unroll
    for (int r = 0; r < 4; ++r) {
      const int co = co0 + cm0 + i * 16 + quad * 4 + r;
      const float bi = bias[co];
#pragma unroll
      for (int j = 0; j < 4; ++j) {
        const int l = l0 + cn0 + j * 16 + col;
        const float y = acc[i][j][r] + bi;
        if (mode == 0) {
          const int xx = (co << 2) + (l >> 9);
          const int hh = (l >> 6) & 7;
          const int dd = l & 63;
          ((ushort*)outp)[((size_t)(b * NH + hh) * LL + xx) * HD + dd] = f2bf(y);
        } else if (mode == 1) {
          const int xx = (co << 2) + (l >> 9);
          const int hh = (l >> 6) & 7;
          const int dd = l & 63;
          ((ushort*)outp)[((size_t)(b * NH + hh) * HD + dd) * LL + xx] = f2bf(y);
        } else {
          ((float*)outp)[(size_t)(b * CC + co) * LL + l] = y;
        }
      }
    }
  }
}

__global__ __launch_bounds__(256, 2)
void conv_k(const ushort* __restrict__ xT, const ushort* __restrict__ Wt,
            const float* __restrict__ bias, void* __restrict__ outp, int mode)
{
  const int b = blockIdx.z;
  conv_body(xT + (size_t)b * (LPAD * CC), Wt, bias, outp, mode, b);
}

// fused q/k/v conv: z = var*4 + b ; var 0,1 -> mode 0, var 2 -> mode 1
__global__ __launch_bounds__(256, 2)
void conv3_k(const ushort* __restrict__ xq, const ushort* __restrict__ xk,
             const ushort* __restrict__ xv, const ushort* __restrict__ Wt,
             const float* __restrict__ b0, const float* __restrict__ b1,
             const float* __restrict__ b2, ushort* __restrict__ o0,
             ushort* __restrict__ o1, ushort* __restrict__ o2)
{
  const int z = blockIdx.z;
  const int b = z & 3, var = z >> 2;
  const ushort* xT = (var == 0) ? xq : (var == 1) ? xk : xv;
  const float* bias = (var == 0) ? b0 : (var == 1) ? b1 : b2;
  ushort* outp = (var == 0) ? o0 : (var == 1) ? o1 : o2;
  conv_body(xT + (size_t)b * (LPAD * CC), Wt + (size_t)var * CC * KK, bias, outp,
            (var == 2) ? 1 : 0, b);
}

// ---------------------------------------------------------------------------
// Attention v4 (split-y + XCD swizzle + hoisted loads): block = 4 waves
// sharing the SAME 32 Q-rows; wave wv covers y-range [wv*512, wv*512+512) —
// partials purely additive (no max-subtraction).  1-D grid 2048 decoded so
// each XCD owns 4 whole (b,h) heads: K/V (2 MB) stays resident in that XCD's
// private L2.  All 16 K/V fragment loads per y-tile issue up-front (MLP=16).
// Denominator via ones-MFMA.  Cross-wave reduce in dead Ps LDS.
// ---------------------------------------------------------------------------
__global__ __launch_bounds__(256, 3)
void attn_k(const ushort* __restrict__ qh, const ushort* __restrict__ kh,
            const ushort* __restrict__ vt, ushort* __restrict__ o)
{
  // XCD-aware decode: id%8 = XCD (round-robin dispatch heuristic).
  const int id   = blockIdx.x;
  const int xcd  = id & 7;
  const int slot = id >> 3;          // 0..255
  const int bh   = xcd * 4 + (slot >> 6);
  const int x0   = (slot & 63) * 32;
  const int b = bh >> 3, h = bh & 7;
  const int tid = threadIdx.x, lane = tid & 63, wv = tid >> 6;
  const int col = lane & 15, quad = lane >> 4;
  const int wx = wv * 32;          // wave-private P rows

  __shared__ ushort Ps[128 * 88];  // 22528 B; re-used as f32 reduce slots later

  const ushort* Qg = qh + (size_t)bh * (LL * HD);
  const ushort* Kg = kh + (size_t)bh * (LL * HD);
  const ushort* Vg = vt + (size_t)bh * (HD * LL);

  // Q fragments (A-operand layout: m=lane&15, k=quad*8+j)
  bf16x8 aq[2][2];
#pragma unroll
  for (int i = 0; i < 2; ++i)
#pragma unroll
    for (int kk = 0; kk < 2; ++kk)
      aq[i][kk] = *(const bf16x8*)(Qg + (size_t)(x0 + i * 16 + col) * HD + kk * 32 + quad * 8);

  const short one = (short)0x3F80;  // bf16 1.0
  const bf16x8 ones = {one, one, one, one, one, one, one, one};

  f32x4 oacc[2][4] = {};
  f32x4 dacc[2] = {};

  const int ybeg = wv * 8;        // 8 y-tiles of 64 per wave
  for (int yt = ybeg; yt < ybeg + 8; ++yt) {
    const int y0 = yt * 64;
    // hoist ALL K and V fragment loads (16 outstanding dwordx4)
    bf16x8 bk[2][4], bv[2][4];
#pragma unroll
    for (int kk = 0; kk < 2; ++kk)
#pragma unroll
      for (int j = 0; j < 4; ++j) {
        bk[kk][j] = *(const bf16x8*)(Kg + (size_t)(y0 + j * 16 + col) * HD + kk * 32 + quad * 8);
        bv[kk][j] = *(const bf16x8*)(Vg + (size_t)(j * 16 + col) * LL + y0 + kk * 32 + quad * 8);
      }
    // S = Q K^T
    f32x4 sacc[2][4] = {};
#pragma unroll
    for (int kk = 0; kk < 2; ++kk)
#pragma unroll
      for (int j = 0; j < 4; ++j) {
        sacc[0][j] = __builtin_amdgcn_mfma_f32_16x16x32_bf16(aq[0][kk], bk[kk][j], sacc[0][j], 0, 0, 0);
        sacc[1][j] = __builtin_amdgcn_mfma_f32_16x16x32_bf16(aq[1][kk], bk[kk][j], sacc[1][j], 0, 0, 0);
      }
    // exp, packed bf16 cvt, P -> wave-private LDS rows
#pragma unroll
    for (int i = 0; i < 2; ++i)
#pragma unroll
      for (int j = 0; j < 4; ++j)
#pragma unroll
        for (int r = 0; r < 4; r += 2) {
          const float p0 = __expf(sacc[i][j][r] * 0.015625f);
          const float p1 = __expf(sacc[i][j][r + 1] * 0.015625f);
          union { __hip_bfloat162 h; ushort2 u; } cv;
          cv.h = __float22bfloat162_rn(make_float2(p0, p1));
          Ps[(wx + i * 16 + quad * 4 + r) * 88 + j * 16 + col] = cv.u.x;
          Ps[(wx + i * 16 + quad * 4 + r + 1) * 88 + j * 16 + col] = cv.u.y;
        }
    // O += P V ; denom += P * ones
#pragma unroll
    for (int kk = 0; kk < 2; ++kk) {
      bf16x8 ap0 = *(const bf16x8*)&Ps[(wx + col) * 88 + kk * 32 + quad * 8];
      bf16x8 ap1 = *(const bf16x8*)&Ps[(wx + 16 + col) * 88 + kk * 32 + quad * 8];
      dacc[0] = __builtin_amdgcn_mfma_f32_16x16x32_bf16(ap0, ones, dacc[0], 0, 0, 0);
      dacc[1] = __builtin_amdgcn_mfma_f32_16x16x32_bf16(ap1, ones, dacc[1], 0, 0, 0);
#pragma unroll
      for (int j = 0; j < 4; ++j) {
        oacc[0][j] = __builtin_amdgcn_mfma_f32_16x16x32_bf16(ap0, bv[kk][j], oacc[0][j], 0, 0, 0);
        oacc[1][j] = __builtin_amdgcn_mfma_f32_16x16x32_bf16(ap1, bv[kk][j], oacc[1][j], 0, 0, 0);
      }
    }
  }

  // ---- cross-wave reduction (Ps region is dead after this barrier) ----
  float* F  = (float*)Ps;             // 2 slots x 32 rows x stride 66 f32
  float* Dd = (float*)(Ps + 8448);    // 2 slots x 32 f32
  __syncthreads();
  if (wv >= 2) {
    const int s = wv - 2;
#pragma unroll
    for (int i = 0; i < 2; ++i) {
#pragma unroll
      for (int r = 0; r < 4; ++r) {
        const int row = i * 16 + quad * 4 + r;
#pragma unroll
        for (int j = 0; j < 4; ++j)
          F[s * 2112 + row * 66 + j * 16 + col] = oacc[i][j][r];
        Dd[s * 32 + row] = dacc[i][r];
      }
    }
  }
  __syncthreads();
  if (wv < 2) {
    const int s = wv;
#pragma unroll
    for (int i = 0; i < 2; ++i)
#pragma unroll
      for (int r = 0; r < 4; ++r) {
        const int row = i * 16 + quad * 4 + r;
#pragma unroll
        for (int j = 0; j < 4; ++j)
          oacc[i][j][r] += F[s * 2112 + row * 66 + j * 16 + col];
        dacc[i][r] += Dd[s * 32 + row];
      }
  }
  __syncthreads();
  if (wv == 1) {
#pragma unroll
    for (int i = 0; i < 2; ++i)
#pragma unroll
      for (int r = 0; r < 4; ++r) {
        const int row = i * 16 + quad * 4 + r;
#pragma unroll
        for (int j = 0; j < 4; ++j)
          F[row * 66 + j * 16 + col] = oacc[i][j][r];
        Dd[row] = dacc[i][r];
      }
  }
  __syncthreads();
  if (wv == 0) {
#pragma unroll
    for (int i = 0; i < 2; ++i)
#pragma unroll
      for (int r = 0; r < 4; ++r) {
        const int row = i * 16 + quad * 4 + r;
        const int xg = x0 + row;
        float dn = dacc[i][r] + Dd[row];
        const float inv = 1.f / dn;
#pragma unroll
        for (int j = 0; j < 4; ++j) {
          const float ov = oacc[i][j][r] + F[row * 66 + j * 16 + col];
          const int d = j * 16 + col;
          const int flat = xg * 512 + h * 64 + d;
          const int c = flat >> 11, l = flat & 2047;
          o[((size_t)(b * CC + c) << 11) + l] = f2bf(ov * inv);
        }
      }
  }
}

// ---------------------------------------------------------------------------
extern "C" void kernel_launch(void* const* d_in, const int* in_sizes, int n_in,
                              void* d_out, int out_size, void* d_ws, size_t ws_size,
                              hipStream_t stream) {
  const float* q    = (const float*)d_in[0];
  const float* k    = (const float*)d_in[1];
  const float* v    = (const float*)d_in[2];
  const float* wq_w = (const float*)d_in[3];
  const float* wq_b = (const float*)d_in[4];
  const float* wk_w = (const float*)d_in[5];
  const float* wk_b = (const float*)d_in[6];
  const float* wv_w = (const float*)d_in[7];
  const float* wv_b = (const float*)d_in[8];
  const float* fc_w = (const float*)d_in[9];
  const float* fc_b = (const float*)d_in[10];

  char* ws = (char*)d_ws;
  const size_t WSZ = (size_t)CC * KK * sizeof(ushort);            // 1.5 MB per conv
  const size_t HSZ = (size_t)BB * NH * LL * HD * sizeof(ushort);  // 8.39 MB per head tensor
  const size_t XSZ = (size_t)BB * LPAD * CC * sizeof(ushort);     // 8.40 MB padded xT
  const size_t FUSED_NEED = 4 * WSZ + 3 * HSZ + 3 * XSZ;          // ~56.65 MB

  ushort* Wt = (ushort*)(ws);
  prep_w<<<(4 * CC * KK + 255) / 256, 256, 0, stream>>>(wq_w, wk_w, wv_w, fc_w, Wt);

  if (ws_size >= FUSED_NEED) {
    // fused path: 3 xT buffers live at once -> one transpose + one conv launch
    ushort* qh  = (ushort*)(ws + 4 * WSZ);
    ushort* kh  = (ushort*)(ws + 4 * WSZ + HSZ);
    ushort* vt  = (ushort*)(ws + 4 * WSZ + 2 * HSZ);
    ushort* xTq = (ushort*)(ws + 4 * WSZ + 3 * HSZ);
    ushort* xTk = (ushort*)(ws + 4 * WSZ + 3 * HSZ + XSZ);
    ushort* xTv = (ushort*)(ws + 4 * WSZ + 3 * HSZ + 2 * XSZ);
    ushort* ob  = xTq;   // attn output [b][c][l]; xT buffers dead after conv3
    ushort* obT = qh;    // padded transpose of ob; spills 8 KB into kh (dead)

    transpose3_k<<<dim3(32, 8, 12), 256, 0, stream>>>(q, k, v, xTq, xTk, xTv);
    conv3_k<<<dim3(16, 8, 12), 256, 0, stream>>>(xTq, xTk, xTv, Wt,
                                                 wq_b, wk_b, wv_b, qh, kh, vt);
    attn_k<<<2048, 256, 0, stream>>>(qh, kh, vt, ob);
    transpose_k<ushort><<<dim3(32, 8, 4), 256, 0, stream>>>(ob, obT);
    conv_k<<<dim3(16, 8, 4), 256, 0, stream>>>(obT, Wt + 3 * CC * KK, fc_b,
                                               (float*)d_out, 2);
  } else {
    // sequential fallback (proven 39.85 MB layout)
    ushort* qh  = (ushort*)(ws + 4 * WSZ);
    ushort* kh  = (ushort*)(ws + 4 * WSZ + HSZ);
    ushort* vt  = (ushort*)(ws + 4 * WSZ + 2 * HSZ);
    ushort* xTb = (ushort*)(ws + 4 * WSZ + 3 * HSZ);
    ushort* ob  = xTb;
    ushort* obT = qh;

    transpose_k<float><<<dim3(32, 8, 4), 256, 0, stream>>>(q, xTb);
    conv_k<<<dim3(16, 8, 4), 256, 0, stream>>>(xTb, Wt + 0 * CC * KK, wq_b, qh, 0);
    transpose_k<float><<<dim3(32, 8, 4), 256, 0, stream>>>(k, xTb);
    conv_k<<<dim3(16, 8, 4), 256, 0, stream>>>(xTb, Wt + 1 * CC * KK, wk_b, kh, 0);
    transpose_k<float><<<dim3(32, 8, 4), 256, 0, stream>>>(v, xTb);
    conv_k<<<dim3(16, 8, 4), 256, 0, stream>>>(xTb, Wt + 2 * CC * KK, wv_b, vt, 1);
    attn_k<<<2048, 256, 0, stream>>>(qh, kh, vt, ob);
    transpose_k<ushort><<<dim3(32, 8, 4), 256, 0, stream>>>(ob, obT);
    conv_k<<<dim3(16, 8, 4), 256, 0, stream>>>(obT, Wt + 3 * CC * KK, fc_b,
                                               (float*)d_out, 2);
  }
}

// Round 6
// 264.273 us; speedup vs baseline: 1.7312x; 1.2966x over previous
//
#include <hip/hip_runtime.h>
#include <hip/hip_bf16.h>

#define BB 4
#define NH 8
#define HD 64
#define CC 512
#define LL 2048
#define KK 1536   // C*3, K index = t*512 + ci
#define LPAD 2050 // padded rows of xT: row 0 and row 2049 are zeros

typedef float f32x4 __attribute__((ext_vector_type(4)));
typedef short bf16x8 __attribute__((ext_vector_type(8)));

static __device__ __forceinline__ ushort f2bf(float f) {
  union { float f; unsigned u; } v; v.f = f;
  unsigned r = v.u + 0x7fffu + ((v.u >> 16) & 1u);   // RNE
  return (ushort)(r >> 16);
}
static __device__ __forceinline__ void gload16(const ushort* g, ushort* l) {
  __builtin_amdgcn_global_load_lds((const __attribute__((address_space(1))) void*)g,
                                   (__attribute__((address_space(3))) void*)l, 16, 0, 0);
}

// ---------------------------------------------------------------------------
// Weight prep: W[co][ci][t] fp32 -> W'[co][t*512+ci] bf16, for all 4 convs.
// ---------------------------------------------------------------------------
__global__ void prep_w(const float* __restrict__ w0, const float* __restrict__ w1,
                       const float* __restrict__ w2, const float* __restrict__ w3,
                       ushort* __restrict__ out)
{
  int i = blockIdx.x * 256 + threadIdx.x;
  const int per = CC * KK;
  if (i >= 4 * per) return;
  int cidx = i / per;
  int rem  = i - cidx * per;
  int co   = rem / KK;
  int kk   = rem - co * KK;
  int t = kk >> 9, ci = kk & 511;
  const float* w = (cidx == 0) ? w0 : (cidx == 1) ? w1 : (cidx == 2) ? w2 : w3;
  out[i] = f2bf(w[((size_t)co * CC + ci) * 3 + t]);
}

// ---------------------------------------------------------------------------
// Transpose+cast body: xb[c][l] fp32 -> ob[l+1][c] bf16, zero halo rows.
// ---------------------------------------------------------------------------
__device__ __forceinline__ void transpose_body(const float* __restrict__ xb,
                                               ushort* __restrict__ ob)
{
  const int c0 = blockIdx.y * 64;
  const int l0 = blockIdx.x * 64;
  const int tid = threadIdx.x;
  __shared__ ushort T[64 * 72];
  {
    const int rr = tid >> 4;      // 0..15
    const int f4 = tid & 15;      // 0..15
#pragma unroll
    for (int it = 0; it < 4; ++it) {
      const int cc = rr + it * 16;
      ushort s[4];
      float4 vv = *(const float4*)(xb + (size_t)(c0 + cc) * LL + l0 + f4 * 4);
      s[0] = f2bf(vv.x); s[1] = f2bf(vv.y); s[2] = f2bf(vv.z); s[3] = f2bf(vv.w);
      *(ushort4*)&T[cc * 72 + f4 * 4] = *(ushort4*)s;
    }
  }
  __syncthreads();
  {
    const int lr = tid >> 3;     // 0..31
    const int ch = tid & 7;      // 0..7
#pragma unroll
    for (int it = 0; it < 2; ++it) {
      const int ll = lr + it * 32;
      ushort tmp[8];
#pragma unroll
      for (int e = 0; e < 8; ++e) tmp[e] = T[(ch * 8 + e) * 72 + ll];
      *(uint4*)(ob + (size_t)(l0 + ll + 1) * CC + c0 + ch * 8) = *(uint4*)tmp;
    }
  }
  // zero the halo rows
  if (blockIdx.x == 0 && tid < 8) {
    uint4 z4 = make_uint4(0, 0, 0, 0);
    *(uint4*)(ob + c0 + tid * 8) = z4;
  }
  if (blockIdx.x == (LL / 64 - 1) && tid >= 248) {
    uint4 z4 = make_uint4(0, 0, 0, 0);
    *(uint4*)(ob + (size_t)(LPAD - 1) * CC + c0 + (tid - 248) * 8) = z4;
  }
}

__global__ __launch_bounds__(256, 2)
void transpose_k(const float* __restrict__ in, ushort* __restrict__ outT)
{
  const int b = blockIdx.z;
  transpose_body(in + (size_t)b * CC * LL, outT + (size_t)b * (LPAD * CC));
}

// fused q/k/v transpose: z = var*4 + b
__global__ __launch_bounds__(256, 2)
void transpose3_k(const float* __restrict__ q, const float* __restrict__ k,
                  const float* __restrict__ v, ushort* __restrict__ xq,
                  ushort* __restrict__ xk, ushort* __restrict__ xv)
{
  const int z = blockIdx.z;
  const int b = z & 3, var = z >> 2;
  const float* in = (var == 0) ? q : (var == 1) ? k : v;
  ushort* out = (var == 0) ? xq : (var == 1) ? xk : xv;
  transpose_body(in + (size_t)b * CC * LL, out + (size_t)b * (LPAD * CC));
}

// ---------------------------------------------------------------------------
// conv1d(k=3,same) as implicit GEMM, m97-shape tile: M=128(co) x N=128(l),
// BK=64, 4 waves 2x2, 4x4 acc/wave = 32 MFMA/wave/iter.  Staging = 8x
// global_load_lds(16B)/thread with XOR chunk swizzle on the GLOBAL address.
// mode 0: heads [b][h][x][d] bf16 (q,k) | 1: heads-T [b][h][d][x] bf16 (v)
// mode 2: [b][co][l] fp32 (final fc)
// ---------------------------------------------------------------------------
__device__ __forceinline__ void conv_body(const ushort* __restrict__ xb,
                                          const ushort* __restrict__ Wt,
                                          const float* __restrict__ bias,
                                          void* __restrict__ outp, int mode, int b)
{
  const int co0 = blockIdx.y * 128;
  const int l0  = blockIdx.x * 128;
  const int tid = threadIdx.x;
  const int lane = tid & 63;
  const int w    = tid >> 6;
  const int col  = lane & 15, quad = lane >> 4;

  __shared__ ushort Asl[128 * 64];   // 16 KB
  __shared__ ushort Bsl[128 * 64];   // 16 KB

  const int sr = tid >> 3;                 // 0..31
  const int g8 = ((tid & 7) ^ (sr & 7)) * 8;
  const ushort* ag  = Wt + (size_t)(co0 + sr) * KK + g8;
  const ushort* bg  = xb + (size_t)(l0 + sr) * CC + g8;
  ushort* alds = &Asl[tid * 8];
  ushort* blds = &Bsl[tid * 8];

  f32x4 acc[4][4] = {};
  const int wm = (w & 1) * 64;
  const int wn = (w >> 1) * 64;
  const int c7 = col & 7;

  for (int k0 = 0; k0 < KK; k0 += 64) {
#pragma unroll
    for (int r2 = 0; r2 < 4; ++r2) {
      gload16(ag + (size_t)(r2 * 32) * KK + k0, alds + r2 * 2048);
      gload16(bg + (size_t)(r2 * 32) * CC + k0, blds + r2 * 2048);
    }
    __syncthreads();
#pragma unroll
    for (int kk = 0; kk < 2; ++kk) {
      bf16x8 af[4], bfr[4];
#pragma unroll
      for (int i = 0; i < 4; ++i)
        af[i] = *(const bf16x8*)&Asl[(wm + i * 16 + col) * 64 + (((kk * 4 + quad) ^ c7) * 8)];
#pragma unroll
      for (int j = 0; j < 4; ++j)
        bfr[j] = *(const bf16x8*)&Bsl[(wn + j * 16 + col) * 64 + (((kk * 4 + quad) ^ c7) * 8)];
#pragma unroll
      for (int i = 0; i < 4; ++i)
#pragma unroll
        for (int j = 0; j < 4; ++j)
          acc[i][j] = __builtin_amdgcn_mfma_f32_16x16x32_bf16(af[i], bfr[j], acc[i][j], 0, 0, 0);
    }
    __syncthreads();
  }

  // epilogue: C/D layout row = quad*4+r (co), col = lane&15 (l)
#pragma unroll
  for (int i = 0; i < 4; ++i) {
#pragma unroll
    for (int r = 0; r < 4; ++r) {
      const int co = co0 + wm + i * 16 + quad * 4 + r;
      const float bi = bias[co];
#pragma unroll
      for (int j = 0; j < 4; ++j) {
        const int l = l0 + wn + j * 16 + col;
        const float y = acc[i][j][r] + bi;
        if (mode == 0) {
          const int xx = (co << 2) + (l >> 9);
          const int hh = (l >> 6) & 7;
          const int dd = l & 63;
          ((ushort*)outp)[((size_t)(b * NH + hh) * LL + xx) * HD + dd] = f2bf(y);
        } else if (mode == 1) {
          const int xx = (co << 2) + (l >> 9);
          const int hh = (l >> 6) & 7;
          const int dd = l & 63;
          ((ushort*)outp)[((size_t)(b * NH + hh) * HD + dd) * LL + xx] = f2bf(y);
        } else {
          ((float*)outp)[(size_t)(b * CC + co) * LL + l] = y;
        }
      }
    }
  }
}

__global__ __launch_bounds__(256, 3)
void conv_k(const ushort* __restrict__ xT, const ushort* __restrict__ Wt,
            const float* __restrict__ bias, void* __restrict__ outp, int mode)
{
  const int b = blockIdx.z;
  conv_body(xT + (size_t)b * (LPAD * CC), Wt, bias, outp, mode, b);
}

// fused q/k/v conv: z = var*4 + b ; var 0,1 -> mode 0, var 2 -> mode 1
__global__ __launch_bounds__(256, 3)
void conv3_k(const ushort* __restrict__ xq, const ushort* __restrict__ xk,
             const ushort* __restrict__ xv, const ushort* __restrict__ Wt,
             const float* __restrict__ b0, const float* __restrict__ b1,
             const float* __restrict__ b2, ushort* __restrict__ o0,
             ushort* __restrict__ o1, ushort* __restrict__ o2)
{
  const int z = blockIdx.z;
  const int b = z & 3, var = z >> 2;
  const ushort* xT = (var == 0) ? xq : (var == 1) ? xk : xv;
  const float* bias = (var == 0) ? b0 : (var == 1) ? b1 : b2;
  ushort* outp = (var == 0) ? o0 : (var == 1) ? o1 : o2;
  conv_body(xT + (size_t)b * (LPAD * CC), Wt + (size_t)var * CC * KK, bias, outp,
            (var == 2) ? 1 : 0, b);
}

// ---------------------------------------------------------------------------
// Attention v5: block = 4 waves x 32 Q-rows (128 Q/block); each wave covers
// ALL y for its rows (no cross-wave reduce).  K/V staged via async
// global_load_lds into a DOUBLE-BUFFERED 32 KB LDS region; one barrier per
// y-tile; prefetch of tile t+1 issued right after the barrier so it overlaps
// the whole compute phase of tile t.  Denominator via ones-MFMA.  P takes the
// verified LDS round-trip (wave-private rows).  Output written DIRECTLY in
// padded-transposed [b][l+1][c] bf16 layout for the fc conv (kills the 4th
// transpose kernel); halo rows zeroed by the x0==0 block of each (b,h).
// Grid 512 decoded XCD-aware (4 whole heads per XCD -> K/V L2-resident).
// ---------------------------------------------------------------------------
__global__ __launch_bounds__(256, 2)
void attn_k(const ushort* __restrict__ qh, const ushort* __restrict__ kh,
            const ushort* __restrict__ vt, ushort* __restrict__ obT)
{
  const int id   = blockIdx.x;
  const int xcd  = id & 7;
  const int slot = id >> 3;          // 0..63
  const int bh   = xcd * 4 + (slot >> 4);
  const int x0   = (slot & 15) * 128;
  const int b = bh >> 3, h = bh & 7;
  const int tid = threadIdx.x, lane = tid & 63, wv = tid >> 6;
  const int col = lane & 15, quad = lane >> 4;
  const int wx = wv * 32;            // wave-private Q rows / P rows
  const int c7 = col & 7;

  __shared__ ushort Kv[2][8192];     // [buf][ K 64x64 | V^T 64x64 ]  32 KB
  __shared__ ushort Ps[128 * 88];    // 22.5 KB

  const ushort* Qg = qh + (size_t)bh * (LL * HD);
  const ushort* Kg = kh + (size_t)bh * (LL * HD);
  const ushort* Vg = vt + (size_t)bh * (HD * LL);
  ushort* ob = obT + (size_t)b * (LPAD * CC);

  // staging addresses (XOR chunk swizzle on the global side)
  const int sr = tid >> 3;                 // 0..31
  const int g8 = ((tid & 7) ^ (sr & 7)) * 8;

  // Q fragments (A-operand layout: m=lane&15, k=quad*8+j)
  bf16x8 aq[2][2];
#pragma unroll
  for (int i = 0; i < 2; ++i)
#pragma unroll
    for (int kk = 0; kk < 2; ++kk)
      aq[i][kk] = *(const bf16x8*)(Qg + (size_t)(x0 + wx + i * 16 + col) * HD + kk * 32 + quad * 8);

  const short one = (short)0x3F80;  // bf16 1.0
  const bf16x8 ones = {one, one, one, one, one, one, one, one};

  f32x4 oacc[2][4] = {};
  f32x4 dacc[2] = {};

  // prefetch y-tile 0 into buf 0
  {
    ushort* kb = &Kv[0][tid * 8];
    gload16(Kg + (size_t)sr * HD + g8, kb);
    gload16(Kg + (size_t)(32 + sr) * HD + g8, kb + 2048);
    gload16(Vg + (size_t)sr * LL + g8, kb + 4096);
    gload16(Vg + (size_t)(32 + sr) * LL + g8, kb + 6144);
  }

  for (int yt = 0; yt < 32; ++yt) {
    const int cur = yt & 1;
    __syncthreads();   // drains prefetch of buf[cur]; fences buf[1-cur] readers
    if (yt + 1 < 32) {
      const int y1 = (yt + 1) * 64;
      ushort* kb = &Kv[1 - cur][tid * 8];
      gload16(Kg + (size_t)(y1 + sr) * HD + g8, kb);
      gload16(Kg + (size_t)(y1 + 32 + sr) * HD + g8, kb + 2048);
      gload16(Vg + (size_t)sr * LL + y1 + g8, kb + 4096);
      gload16(Vg + (size_t)(32 + sr) * LL + y1 + g8, kb + 6144);
    }
    const ushort* Kb = &Kv[cur][0];
    const ushort* Vb = &Kv[cur][4096];

    // S = Q K^T   (K-tile rows y, k=d; swizzled chunks)
    f32x4 sacc[2][4] = {};
#pragma unroll
    for (int kk = 0; kk < 2; ++kk)
#pragma unroll
      for (int j = 0; j < 4; ++j) {
        bf16x8 bk = *(const bf16x8*)&Kb[(j * 16 + col) * 64 + (((kk * 4 + quad) ^ c7) * 8)];
        sacc[0][j] = __builtin_amdgcn_mfma_f32_16x16x32_bf16(aq[0][kk], bk, sacc[0][j], 0, 0, 0);
        sacc[1][j] = __builtin_amdgcn_mfma_f32_16x16x32_bf16(aq[1][kk], bk, sacc[1][j], 0, 0, 0);
      }
    // exp, packed bf16 cvt, P -> wave-private LDS rows
#pragma unroll
    for (int i = 0; i < 2; ++i)
#pragma unroll
      for (int j = 0; j < 4; ++j)
#pragma unroll
        for (int r = 0; r < 4; r += 2) {
          const float p0 = __expf(sacc[i][j][r] * 0.015625f);
          const float p1 = __expf(sacc[i][j][r + 1] * 0.015625f);
          union { __hip_bfloat162 h; ushort2 u; } cv;
          cv.h = __float22bfloat162_rn(make_float2(p0, p1));
          Ps[(wx + i * 16 + quad * 4 + r) * 88 + j * 16 + col] = cv.u.x;
          Ps[(wx + i * 16 + quad * 4 + r + 1) * 88 + j * 16 + col] = cv.u.y;
        }
    // O += P V ; denom += P * ones   (V^T-tile rows d, k=y)
#pragma unroll
    for (int kk = 0; kk < 2; ++kk) {
      bf16x8 ap0 = *(const bf16x8*)&Ps[(wx + col) * 88 + kk * 32 + quad * 8];
      bf16x8 ap1 = *(const bf16x8*)&Ps[(wx + 16 + col) * 88 + kk * 32 + quad * 8];
      dacc[0] = __builtin_amdgcn_mfma_f32_16x16x32_bf16(ap0, ones, dacc[0], 0, 0, 0);
      dacc[1] = __builtin_amdgcn_mfma_f32_16x16x32_bf16(ap1, ones, dacc[1], 0, 0, 0);
#pragma unroll
      for (int j = 0; j < 4; ++j) {
        bf16x8 bv = *(const bf16x8*)&Vb[(j * 16 + col) * 64 + (((kk * 4 + quad) ^ c7) * 8)];
        oacc[0][j] = __builtin_amdgcn_mfma_f32_16x16x32_bf16(ap0, bv, oacc[0][j], 0, 0, 0);
        oacc[1][j] = __builtin_amdgcn_mfma_f32_16x16x32_bf16(ap1, bv, oacc[1][j], 0, 0, 0);
      }
    }
  }

  // normalize + scatter DIRECTLY to padded-transposed [b][l+1][c] bf16
#pragma unroll
  for (int i = 0; i < 2; ++i) {
#pragma unroll
    for (int r = 0; r < 4; ++r) {
      const int xg = x0 + wx + i * 16 + quad * 4 + r;
      const float inv = 1.f / dacc[i][r];
#pragma unroll
      for (int j = 0; j < 4; ++j) {
        const int d = j * 16 + col;
        const int flat = xg * 512 + h * 64 + d;
        const int c = flat >> 11, l = flat & 2047;
        ob[(size_t)(l + 1) * CC + c] = f2bf(oacc[i][j][r] * inv);
      }
    }
  }
  // halo rows (l=-1 and l=2048) zeroed once per (b,h) by the x0==0 block
  if ((slot & 15) == 0 && tid < 128) {
    const int row = tid >> 6;          // 0 or 1
    const int cc  = h * 64 + (tid & 63);
    ob[(size_t)(row ? (LPAD - 1) : 0) * CC + cc] = 0;
  }
}

// ---------------------------------------------------------------------------
extern "C" void kernel_launch(void* const* d_in, const int* in_sizes, int n_in,
                              void* d_out, int out_size, void* d_ws, size_t ws_size,
                              hipStream_t stream) {
  const float* q    = (const float*)d_in[0];
  const float* k    = (const float*)d_in[1];
  const float* v    = (const float*)d_in[2];
  const float* wq_w = (const float*)d_in[3];
  const float* wq_b = (const float*)d_in[4];
  const float* wk_w = (const float*)d_in[5];
  const float* wk_b = (const float*)d_in[6];
  const float* wv_w = (const float*)d_in[7];
  const float* wv_b = (const float*)d_in[8];
  const float* fc_w = (const float*)d_in[9];
  const float* fc_b = (const float*)d_in[10];

  char* ws = (char*)d_ws;
  const size_t WSZ = (size_t)CC * KK * sizeof(ushort);            // 1.5 MB per conv
  const size_t HSZ = (size_t)BB * NH * LL * HD * sizeof(ushort);  // 8.39 MB per head tensor
  const size_t XSZ = (size_t)BB * LPAD * CC * sizeof(ushort);     // 8.40 MB padded xT
  const size_t FUSED_NEED = 4 * WSZ + 3 * HSZ + 3 * XSZ;          // ~56.65 MB

  ushort* Wt = (ushort*)(ws);
  prep_w<<<(4 * CC * KK + 255) / 256, 256, 0, stream>>>(wq_w, wk_w, wv_w, fc_w, Wt);

  if (ws_size >= FUSED_NEED) {
    ushort* qh  = (ushort*)(ws + 4 * WSZ);
    ushort* kh  = (ushort*)(ws + 4 * WSZ + HSZ);
    ushort* vt  = (ushort*)(ws + 4 * WSZ + 2 * HSZ);
    ushort* xTq = (ushort*)(ws + 4 * WSZ + 3 * HSZ);
    ushort* xTk = (ushort*)(ws + 4 * WSZ + 3 * HSZ + XSZ);
    ushort* xTv = (ushort*)(ws + 4 * WSZ + 3 * HSZ + 2 * XSZ);
    ushort* obT = xTq;   // attn writes transposed output here (xTq dead after conv3)

    transpose3_k<<<dim3(32, 8, 12), 256, 0, stream>>>(q, k, v, xTq, xTk, xTv);
    conv3_k<<<dim3(16, 4, 12), 256, 0, stream>>>(xTq, xTk, xTv, Wt,
                                                 wq_b, wk_b, wv_b, qh, kh, vt);
    attn_k<<<512, 256, 0, stream>>>(qh, kh, vt, obT);
    conv_k<<<dim3(16, 4, 4), 256, 0, stream>>>(obT, Wt + 3 * CC * KK, fc_b,
                                               (float*)d_out, 2);
  } else {
    // sequential fallback (39.85 MB layout)
    ushort* qh  = (ushort*)(ws + 4 * WSZ);
    ushort* kh  = (ushort*)(ws + 4 * WSZ + HSZ);
    ushort* vt  = (ushort*)(ws + 4 * WSZ + 2 * HSZ);
    ushort* xTb = (ushort*)(ws + 4 * WSZ + 3 * HSZ);
    ushort* obT = xTb;   // xTb dead after v-conv

    transpose_k<<<dim3(32, 8, 4), 256, 0, stream>>>(q, xTb);
    conv_k<<<dim3(16, 4, 4), 256, 0, stream>>>(xTb, Wt + 0 * CC * KK, wq_b, qh, 0);
    transpose_k<<<dim3(32, 8, 4), 256, 0, stream>>>(k, xTb);
    conv_k<<<dim3(16, 4, 4), 256, 0, stream>>>(xTb, Wt + 1 * CC * KK, wk_b, kh, 0);
    transpose_k<<<dim3(32, 8, 4), 256, 0, stream>>>(v, xTb);
    conv_k<<<dim3(16, 4, 4), 256, 0, stream>>>(xTb, Wt + 2 * CC * KK, wv_b, vt, 1);
    attn_k<<<512, 256, 0, stream>>>(qh, kh, vt, obT);
    conv_k<<<dim3(16, 4, 4), 256, 0, stream>>>(obT, Wt + 3 * CC * KK, fc_b,
                                               (float*)d_out, 2);
  }
}